// Round 1
// baseline (814.772 us; speedup 1.0000x reference)
//
#include <hip/hip_runtime.h>
#include <hip/hip_bf16.h>
#include <stdint.h>

#define S_LEN 2048
#define HIDD  4096
#define NH    32
#define NKV   8
#define HD    128
#define NQKV  6144   // (NH + 2*NKV) * HD
#define ATT_SCALE 0.08838834764831845f
#define LOG2E 1.4426950408889634f

typedef unsigned short u16;
typedef __attribute__((ext_vector_type(8))) short short8;
typedef __attribute__((ext_vector_type(4))) float f32x4;

__device__ __forceinline__ unsigned f2bfbits(float f){
  union{float f; unsigned u;} v; v.f = f;
  return (v.u + 0x7FFFu + ((v.u>>16)&1u)) >> 16;
}
__device__ __forceinline__ unsigned packbf(float a, float b){
  return f2bfbits(a) | (f2bfbits(b)<<16);
}

#define GLOAD16(g, l) __builtin_amdgcn_global_load_lds( \
    (__attribute__((address_space(1))) void*)(g), \
    (__attribute__((address_space(3))) void*)(l), 16, 0, 0)

// ---------------- fp32 -> bf16 convert (8 elems/thread) ----------------
__global__ __launch_bounds__(256) void cvt_bf16(const float* __restrict__ in,
                                                u16* __restrict__ out, int n8){
  int i = blockIdx.x*256 + threadIdx.x;
  if (i >= n8) return;
  const float4* p = (const float4*)in;
  float4 a = p[2*i], b = p[2*i+1];
  union { unsigned u[4]; short8 s; } o;
  o.u[0] = packbf(a.x, a.y); o.u[1] = packbf(a.z, a.w);
  o.u[2] = packbf(b.x, b.y); o.u[3] = packbf(b.z, b.w);
  *(short8*)(out + (size_t)i*8) = o.s;
}

// ---------------- bf16 GEMM, C = A * B^T  (A[M][K], B[N][K], C[M][N] fp32) ----
// m97 structure: 128x128 tile, BK=64, 4 waves, global_load_lds staging.
__global__ __launch_bounds__(256) void gemm_bt(const u16* __restrict__ A,
                                               const u16* __restrict__ B,
                                               float* __restrict__ C,
                                               int M, int N, int K){
  __shared__ u16 As[128*64];
  __shared__ u16 Bs[128*64];
  const int tid = threadIdx.x;
  const int w = tid>>6, lane = tid&63, ln = lane&15, g = lane>>4;
  const int m0 = blockIdx.y*128, n0 = blockIdx.x*128;
  const int wr = w>>1, wc = w&1;
  f32x4 acc[4][4];
  #pragma unroll
  for (int m=0;m<4;m++)
    #pragma unroll
    for (int n=0;n<4;n++) acc[m][n] = (f32x4){0.f,0.f,0.f,0.f};

  for (int kt=0; kt<K; kt+=64){
    #pragma unroll
    for (int i=0;i<4;i++){
      int slot = i*256 + tid;
      int row = slot>>3, seg = slot&7;
      const u16* ga = A + (size_t)(m0+row)*K + kt + seg*8;
      GLOAD16(ga, (char*)As + (i*256 + w*64)*16);
      const u16* gb = B + (size_t)(n0+row)*K + kt + seg*8;
      GLOAD16(gb, (char*)Bs + (i*256 + w*64)*16);
    }
    __syncthreads();
    #pragma unroll
    for (int kk=0; kk<2; kk++){
      short8 af[4], bfv[4];
      #pragma unroll
      for (int m=0;m<4;m++)
        af[m] = *(const short8*)((const char*)As + (wr*64 + m*16 + ln)*128 + kk*64 + g*16);
      #pragma unroll
      for (int n=0;n<4;n++)
        bfv[n] = *(const short8*)((const char*)Bs + (wc*64 + n*16 + ln)*128 + kk*64 + g*16);
      #pragma unroll
      for (int m=0;m<4;m++)
        #pragma unroll
        for (int n=0;n<4;n++)
          acc[m][n] = __builtin_amdgcn_mfma_f32_16x16x32_bf16(af[m], bfv[n], acc[m][n], 0,0,0);
    }
    __syncthreads();
  }
  #pragma unroll
  for (int m=0;m<4;m++)
    #pragma unroll
    for (int n=0;n<4;n++)
      #pragma unroll
      for (int r=0;r<4;r++){
        int row = m0 + wr*64 + m*16 + g*4 + r;
        int col = n0 + wc*64 + n*16 + ln;
        C[(size_t)row*N + col] = acc[m][n][r];
      }
}

// ---------------- RMSNorm + RoPE + layout (1 wave per (s, head-slot) row) -----
// QKV fp32 [S][6144]; slots: 0..31 Q heads, 32..39 K heads, 40..47 V heads.
// Lane t holds d=t and d=t+64 (rotate_half partners -> no LDS).
// Outputs: Qn [NH][S][HD] bf16, Kn [NKV][S][HD] bf16, Vt [NKV][HD][S] bf16.
__global__ __launch_bounds__(256) void norm_rope(const float* __restrict__ QKV,
                                                 const float* __restrict__ cosb,
                                                 const float* __restrict__ sinb,
                                                 const float* __restrict__ qw,
                                                 const float* __restrict__ kw,
                                                 u16* __restrict__ Qn,
                                                 u16* __restrict__ Kn,
                                                 u16* __restrict__ Vt){
  int w = threadIdx.x>>6, lane = threadIdx.x&63;
  int row = blockIdx.x*4 + w;              // 0 .. S*48-1
  int s = row / 48, slot = row - s*48;
  const float* src = QKV + (size_t)s*NQKV + slot*HD;
  float x0 = src[lane], x1 = src[lane+64];
  if (slot < 40){
    float ss = x0*x0 + x1*x1;
    #pragma unroll
    for (int off=1; off<64; off<<=1) ss += __shfl_xor(ss, off, 64);
    float r = rsqrtf(ss*(1.0f/128.0f) + 1e-6f);
    const float* wgt = (slot < 32) ? qw : kw;
    float y0 = x0*r*wgt[lane], y1 = x1*r*wgt[lane+64];
    float c0 = cosb[(size_t)s*HD+lane], c1 = cosb[(size_t)s*HD+lane+64];
    float s0 = sinb[(size_t)s*HD+lane], s1 = sinb[(size_t)s*HD+lane+64];
    float o0 = y0*c0 - y1*s0;       // first half: x*cos + (-x2)*sin
    float o1 = y1*c1 + y0*s1;       // second half: x*cos + (x1)*sin
    u16* dst = (slot < 32) ? (Qn + ((size_t)slot*S_LEN + s)*HD)
                           : (Kn + ((size_t)(slot-32)*S_LEN + s)*HD);
    dst[lane]    = (u16)f2bfbits(o0);
    dst[lane+64] = (u16)f2bfbits(o1);
  } else {
    int kvh = slot - 40;
    u16* dst = Vt + (size_t)kvh*HD*S_LEN + s;
    dst[(size_t)lane*S_LEN]      = (u16)f2bfbits(x0);
    dst[(size_t)(lane+64)*S_LEN] = (u16)f2bfbits(x1);
  }
}

// ---------------- flash attention (causal, GQA) ----------------
// Swapped-operand scheme: S^T = mfma(K, Q) so each lane owns one q-row's
// stats (q = lane&15); O^T = mfma(Vt, P^T). BQ=64 (16 rows/wave), BKV=32.
__global__ __launch_bounds__(256) void flash_attn(const u16* __restrict__ Qn,
                                                  const u16* __restrict__ Kn,
                                                  const u16* __restrict__ Vt,
                                                  u16* __restrict__ O){
  const int h = blockIdx.y;
  const int q0 = blockIdx.x*64;
  const int w = threadIdx.x>>6, lane = threadIdx.x&63, ln = lane&15, g = lane>>4;
  const int kvh = h>>2;                       // NH/NKV = 4
  const int qrow = q0 + w*16 + ln;
  const u16* Qh = Qn + (size_t)h*S_LEN*HD;
  const u16* Kh = Kn + (size_t)kvh*S_LEN*HD;
  const u16* Vh = Vt + (size_t)kvh*HD*S_LEN;

  short8 qf[4];
  #pragma unroll
  for (int c=0;c<4;c++)
    qf[c] = *(const short8*)(Qh + (size_t)qrow*HD + c*32 + g*8);

  f32x4 ot[8];
  #pragma unroll
  for (int dt=0;dt<8;dt++) ot[dt] = (f32x4){0.f,0.f,0.f,0.f};
  float m_run = -1e30f, l_run = 0.f;

  const int ntiles = (q0 + w*16 + 16 + 31) >> 5;   // cover kv <= wave's max qrow
  for (int t=0; t<ntiles; t++){
    const int kv0 = t*32;
    f32x4 st[2];
    #pragma unroll
    for (int mt=0; mt<2; mt++){
      f32x4 acc = (f32x4){0.f,0.f,0.f,0.f};
      const u16* kr = Kh + (size_t)(kv0 + mt*16 + ln)*HD + g*8;
      #pragma unroll
      for (int c=0;c<4;c++){
        short8 kf = *(const short8*)(kr + c*32);
        acc = __builtin_amdgcn_mfma_f32_16x16x32_bf16(kf, qf[c], acc, 0,0,0);
      }
      st[mt] = acc;
    }
    // scale + causal mask; per-lane row stats (q = ln, kv = mt*16 + 4g + r)
    float p[2][4];
    float mtile = -1e30f;
    #pragma unroll
    for (int mt=0; mt<2; mt++)
      #pragma unroll
      for (int r=0;r<4;r++){
        int kv = kv0 + mt*16 + 4*g + r;
        float sv = (kv <= qrow) ? st[mt][r]*ATT_SCALE : -1e30f;
        p[mt][r] = sv;
        mtile = fmaxf(mtile, sv);
      }
    mtile = fmaxf(mtile, __shfl_xor(mtile, 16, 64));
    mtile = fmaxf(mtile, __shfl_xor(mtile, 32, 64));
    float m_new = fmaxf(m_run, mtile);
    float l_tile = 0.f;
    #pragma unroll
    for (int mt=0; mt<2; mt++)
      #pragma unroll
      for (int r=0;r<4;r++){
        float e = exp2f((p[mt][r] - m_new)*LOG2E);
        p[mt][r] = e;
        l_tile += e;
      }
    l_tile += __shfl_xor(l_tile, 16, 64);
    l_tile += __shfl_xor(l_tile, 32, 64);
    float alpha = exp2f((m_run - m_new)*LOG2E);
    l_run = l_run*alpha + l_tile;
    m_run = m_new;
    #pragma unroll
    for (int dt=0;dt<8;dt++) ot[dt] *= alpha;

    // P redistribution: held kv = mt*16+4g+r -> need kv = 8g+i (i=0..7)
    unsigned pk00 = packbf(p[0][0], p[0][1]), pk01 = packbf(p[0][2], p[0][3]);
    unsigned pk10 = packbf(p[1][0], p[1][1]), pk11 = packbf(p[1][2], p[1][3]);
    int src0 = (((2*g  )&3)<<4) | ln;
    int src1 = (((2*g+1)&3)<<4) | ln;
    unsigned t00 = (unsigned)__shfl((int)pk00, src0, 64);
    unsigned t10 = (unsigned)__shfl((int)pk10, src0, 64);
    unsigned t01 = (unsigned)__shfl((int)pk01, src0, 64);
    unsigned t11 = (unsigned)__shfl((int)pk11, src0, 64);
    unsigned u00 = (unsigned)__shfl((int)pk00, src1, 64);
    unsigned u10 = (unsigned)__shfl((int)pk10, src1, 64);
    unsigned u01 = (unsigned)__shfl((int)pk01, src1, 64);
    unsigned u11 = (unsigned)__shfl((int)pk11, src1, 64);
    bool hiv = (g >= 2);
    union { unsigned u[4]; short8 s; } pw;
    pw.u[0] = hiv ? t10 : t00;
    pw.u[1] = hiv ? t11 : t01;
    pw.u[2] = hiv ? u10 : u00;
    pw.u[3] = hiv ? u11 : u01;
    short8 pf = pw.s;

    #pragma unroll
    for (int dt=0;dt<8;dt++){
      short8 vf = *(const short8*)(Vh + (size_t)(dt*16 + ln)*S_LEN + kv0 + g*8);
      ot[dt] = __builtin_amdgcn_mfma_f32_16x16x32_bf16(vf, pf, ot[dt], 0,0,0);
    }
  }

  float inv = 1.0f / l_run;
  u16* orow = O + (size_t)qrow*(NH*HD) + h*HD;
  #pragma unroll
  for (int dt=0;dt<8;dt++){
    #pragma unroll
    for (int rr=0; rr<4; rr+=2){
      unsigned pkd = packbf(ot[dt][rr]*inv, ot[dt][rr+1]*inv);
      *(unsigned*)(orow + dt*16 + g*4 + rr) = pkd;
    }
  }
}

// ---------------- host ----------------
extern "C" void kernel_launch(void* const* d_in, const int* in_sizes, int n_in,
                              void* d_out, int out_size, void* d_ws, size_t ws_size,
                              hipStream_t stream){
  (void)in_sizes; (void)n_in; (void)out_size; (void)ws_size;
  const float* hs   = (const float*)d_in[0];
  const float* cosb = (const float*)d_in[1];
  const float* sinb = (const float*)d_in[2];
  const float* Wq   = (const float*)d_in[3];
  const float* Wk   = (const float*)d_in[4];
  const float* Wv   = (const float*)d_in[5];
  const float* Wo   = (const float*)d_in[6];
  const float* qw   = (const float*)d_in[7];
  const float* kw   = (const float*)d_in[8];
  float* out = (float*)d_out;

  char* ws = (char*)d_ws;
  // layout (bytes): Xb 16MiB | WQKV 48MiB (later Wob) | QKV f32 48MiB (later attnB) | Qn 16MiB | Kn 4MiB | Vt 4MiB
  u16*   Xb    = (u16*)  (ws);
  u16*   WQKV  = (u16*)  (ws + 16777216);
  float* QKV   = (float*)(ws + 67108864);
  u16*   attnB = (u16*)  (ws + 67108864);   // overlay: QKV dead after norm_rope
  u16*   Qn    = (u16*)  (ws + 117440512);
  u16*   Kn    = (u16*)  (ws + 134217728);
  u16*   Vt    = (u16*)  (ws + 138412032);
  u16*   Wob   = WQKV;                      // overlay: WQKV dead after GEMM1

  // 1. convert X, Wq|Wk|Wv (packed rows: 0..4095 Q, 4096..5119 K, 5120..6143 V)
  cvt_bf16<<<(S_LEN*HIDD/8)/256, 256, 0, stream>>>(hs, Xb, S_LEN*HIDD/8);
  cvt_bf16<<<(NH*HD*HIDD/8)/256, 256, 0, stream>>>(Wq, WQKV, NH*HD*HIDD/8);
  cvt_bf16<<<(NKV*HD*HIDD/8)/256, 256, 0, stream>>>(Wk, WQKV + (size_t)NH*HD*HIDD, NKV*HD*HIDD/8);
  cvt_bf16<<<(NKV*HD*HIDD/8)/256, 256, 0, stream>>>(Wv, WQKV + (size_t)(NH+NKV)*HD*HIDD, NKV*HD*HIDD/8);
  // 2. QKV = X @ WQKV^T   (fp32 out)
  gemm_bt<<<dim3(NQKV/128, S_LEN/128), 256, 0, stream>>>(Xb, WQKV, QKV, S_LEN, NQKV, HIDD);
  // 3. RMSNorm + RoPE + relayout
  norm_rope<<<(S_LEN*48)/4, 256, 0, stream>>>(QKV, cosb, sinb, qw, kw, Qn, Kn, Vt);
  // 4. convert Wo (into the now-dead WQKV region)
  cvt_bf16<<<(HIDD*NH*HD/8)/256, 256, 0, stream>>>(Wo, Wob, HIDD*NH*HD/8);
  // 5. flash attention -> attnB [S][NH*HD] bf16 (overlays dead QKV region)
  flash_attn<<<dim3(S_LEN/64, NH), 256, 0, stream>>>(Qn, Kn, Vt, attnB);
  // 6. out = attnB @ Wo^T  (fp32 out)
  gemm_bt<<<dim3(HIDD/128, S_LEN/128), 256, 0, stream>>>(attnB, Wob, out, S_LEN, HIDD, HIDD);
}

// Round 2
// 512.273 us; speedup vs baseline: 1.5905x; 1.5905x over previous
//
#include <hip/hip_runtime.h>
#include <hip/hip_bf16.h>
#include <stdint.h>

#define S_LEN 2048
#define HIDD  4096
#define NH    32
#define NKV   8
#define HD    128
#define NQKV  6144   // (NH + 2*NKV) * HD
#define ATT_SCALE 0.08838834764831845f
#define LOG2E 1.4426950408889634f

typedef unsigned short u16;
typedef __attribute__((ext_vector_type(8))) short short8;
typedef __attribute__((ext_vector_type(4))) float f32x4;

__device__ __forceinline__ unsigned f2bfbits(float f){
  union{float f; unsigned u;} v; v.f = f;
  return (v.u + 0x7FFFu + ((v.u>>16)&1u)) >> 16;
}
__device__ __forceinline__ unsigned packbf(float a, float b){
  return f2bfbits(a) | (f2bfbits(b)<<16);
}

#define GLOAD16(g, l) __builtin_amdgcn_global_load_lds( \
    (__attribute__((address_space(1))) void*)(g), \
    (__attribute__((address_space(3))) void*)(l), 16, 0, 0)

// ---------------- fp32 -> bf16 convert (8 elems/thread) ----------------
__global__ __launch_bounds__(256) void cvt_bf16(const float* __restrict__ in,
                                                u16* __restrict__ out, int n8){
  int i = blockIdx.x*256 + threadIdx.x;
  if (i >= n8) return;
  const float4* p = (const float4*)in;
  float4 a = p[2*i], b = p[2*i+1];
  union { unsigned u[4]; short8 s; } o;
  o.u[0] = packbf(a.x, a.y); o.u[1] = packbf(a.z, a.w);
  o.u[2] = packbf(b.x, b.y); o.u[3] = packbf(b.z, b.w);
  *(short8*)(out + (size_t)i*8) = o.s;
}

// ---------------- bf16 GEMM, C = A * B^T  (A[M][K], B[N][K], C[M][N] fp32) ----
__global__ __launch_bounds__(256) void gemm_bt(const u16* __restrict__ A,
                                               const u16* __restrict__ B,
                                               float* __restrict__ C,
                                               int M, int N, int K){
  __shared__ u16 As[128*64];
  __shared__ u16 Bs[128*64];
  const int tid = threadIdx.x;
  const int w = tid>>6, lane = tid&63, ln = lane&15, g = lane>>4;
  const int m0 = blockIdx.y*128, n0 = blockIdx.x*128;
  const int wr = w>>1, wc = w&1;
  f32x4 acc[4][4];
  #pragma unroll
  for (int m=0;m<4;m++)
    #pragma unroll
    for (int n=0;n<4;n++) acc[m][n] = (f32x4){0.f,0.f,0.f,0.f};

  for (int kt=0; kt<K; kt+=64){
    #pragma unroll
    for (int i=0;i<4;i++){
      int slot = i*256 + tid;
      int row = slot>>3, seg = slot&7;
      const u16* ga = A + (size_t)(m0+row)*K + kt + seg*8;
      GLOAD16(ga, (char*)As + (i*256 + w*64)*16);
      const u16* gb = B + (size_t)(n0+row)*K + kt + seg*8;
      GLOAD16(gb, (char*)Bs + (i*256 + w*64)*16);
    }
    __syncthreads();
    #pragma unroll
    for (int kk=0; kk<2; kk++){
      short8 af[4], bfv[4];
      #pragma unroll
      for (int m=0;m<4;m++)
        af[m] = *(const short8*)((const char*)As + (wr*64 + m*16 + ln)*128 + kk*64 + g*16);
      #pragma unroll
      for (int n=0;n<4;n++)
        bfv[n] = *(const short8*)((const char*)Bs + (wc*64 + n*16 + ln)*128 + kk*64 + g*16);
      #pragma unroll
      for (int m=0;m<4;m++)
        #pragma unroll
        for (int n=0;n<4;n++)
          acc[m][n] = __builtin_amdgcn_mfma_f32_16x16x32_bf16(af[m], bfv[n], acc[m][n], 0,0,0);
    }
    __syncthreads();
  }
  #pragma unroll
  for (int m=0;m<4;m++)
    #pragma unroll
    for (int n=0;n<4;n++)
      #pragma unroll
      for (int r=0;r<4;r++){
        int row = m0 + wr*64 + m*16 + g*4 + r;
        int col = n0 + wc*64 + n*16 + ln;
        C[(size_t)row*N + col] = acc[m][n][r];
      }
}

// ---------------- RMSNorm + RoPE + layout (1 wave per (s, head-slot) row) -----
// Q gets ATT_SCALE folded in. Outputs: Qn [NH][S][HD], Kn [NKV][S][HD],
// Vt [NKV][HD][S] (transposed for PV A-operand).
__global__ __launch_bounds__(256) void norm_rope(const float* __restrict__ QKV,
                                                 const float* __restrict__ cosb,
                                                 const float* __restrict__ sinb,
                                                 const float* __restrict__ qw,
                                                 const float* __restrict__ kw,
                                                 u16* __restrict__ Qn,
                                                 u16* __restrict__ Kn,
                                                 u16* __restrict__ Vt){
  int w = threadIdx.x>>6, lane = threadIdx.x&63;
  int row = blockIdx.x*4 + w;              // 0 .. S*48-1
  int s = row / 48, slot = row - s*48;
  const float* src = QKV + (size_t)s*NQKV + slot*HD;
  float x0 = src[lane], x1 = src[lane+64];
  if (slot < 40){
    float ss = x0*x0 + x1*x1;
    #pragma unroll
    for (int off=1; off<64; off<<=1) ss += __shfl_xor(ss, off, 64);
    float r = rsqrtf(ss*(1.0f/128.0f) + 1e-6f);
    const float* wgt = (slot < 32) ? qw : kw;
    float y0 = x0*r*wgt[lane], y1 = x1*r*wgt[lane+64];
    float c0 = cosb[(size_t)s*HD+lane], c1 = cosb[(size_t)s*HD+lane+64];
    float s0 = sinb[(size_t)s*HD+lane], s1 = sinb[(size_t)s*HD+lane+64];
    float o0 = y0*c0 - y1*s0;
    float o1 = y1*c1 + y0*s1;
    float sc = (slot < 32) ? ATT_SCALE : 1.0f;
    u16* dst = (slot < 32) ? (Qn + ((size_t)slot*S_LEN + s)*HD)
                           : (Kn + ((size_t)(slot-32)*S_LEN + s)*HD);
    dst[lane]    = (u16)f2bfbits(o0*sc);
    dst[lane+64] = (u16)f2bfbits(o1*sc);
  } else {
    int kvh = slot - 40;
    u16* dst = Vt + (size_t)kvh*HD*S_LEN + s;
    dst[(size_t)lane*S_LEN]      = (u16)f2bfbits(x0);
    dst[(size_t)(lane+64)*S_LEN] = (u16)f2bfbits(x1);
  }
}

// ---------------- flash attention v2 (causal, GQA) ----------------
// Block = 4 waves x 16 q-rows = 64 q rows, one head. KV tile = 64.
// K/V staged in LDS via global_load_lds (shared by the 4 waves), double-
// buffered 2-phase pipeline, XOR-swizzled reads (pre-swizzled global src).
// Swapped operands: S^T = mfma(K, Q) -> lane-local softmax stats per q-row.
__global__ __launch_bounds__(256) void flash_attn(const u16* __restrict__ Qn,
                                                  const u16* __restrict__ Kn,
                                                  const u16* __restrict__ Vt,
                                                  u16* __restrict__ O){
  __shared__ u16 Ks[2][64*128];   // [kv][d] swizzled, 16KB each
  __shared__ u16 Vs[2][128*64];   // [d][kv] swizzled, 16KB each

  const int h = blockIdx.y;
  const int qb = gridDim.x - 1 - blockIdx.x;   // big blocks first
  const int q0 = qb*64;
  const int w = threadIdx.x>>6, lane = threadIdx.x&63, ln = lane&15, g = lane>>4;
  const int kvh = h>>2;                        // NH/NKV = 4
  const int qrow = q0 + w*16 + ln;
  const u16* Qh = Qn + (size_t)h*S_LEN*HD;
  const u16* Kh = Kn + (size_t)kvh*S_LEN*HD;
  const u16* Vh = Vt + (size_t)kvh*HD*S_LEN;

  short8 qf[4];
  #pragma unroll
  for (int c=0;c<4;c++)
    qf[c] = *(const short8*)(Qh + (size_t)qrow*HD + c*32 + g*8);

  f32x4 ot[8];
  #pragma unroll
  for (int dt=0;dt<8;dt++) ot[dt] = (f32x4){0.f,0.f,0.f,0.f};
  float m_run = -1e30f, l_run = 0.f;

  const int nt = qb + 1;

  // staging: linear LDS dest (wave base + lane*16 HW), inverse-swizzled global src
  const int krow_w = w*4 + g;                  // K row this lane stages (per pass +16)
  const int ksw    = ((krow_w)&7)<<4;
  const int kcol   = ((ln*16) ^ ksw) >> 1;     // u16 offset within K row
  const int vrow_w = w*8 + (lane>>3);          // V row (per pass +32)
  const int vsw    = ((lane>>3)&7)<<4;
  const int vcol   = (((lane&7)*16) ^ vsw) >> 1;

  #define STAGE(bufi, t) { \
    int kv0_ = (t)*64; \
    _Pragma("unroll") \
    for (int p=0;p<4;p++){ \
      const u16* ga = Kh + (size_t)(kv0_ + p*16 + krow_w)*HD + kcol; \
      GLOAD16(ga, (char*)&Ks[bufi][0] + p*4096 + w*1024); \
      const u16* gv = Vh + (size_t)(p*32 + vrow_w)*S_LEN + kv0_ + vcol; \
      GLOAD16(gv, (char*)&Vs[bufi][0] + p*4096 + w*1024); \
    } \
  }

  STAGE(0, 0);
  __syncthreads();

  for (int t=0; t<nt; ++t){
    const int cur = t&1;
    if (t+1 < nt) STAGE(cur^1, t+1);
    const int kv0 = t*64;

    // QK^T: S^T[kv][q] tiles, A = K from LDS, B = qf
    f32x4 st[4];
    #pragma unroll
    for (int mt=0; mt<4; mt++){
      f32x4 acc = (f32x4){0.f,0.f,0.f,0.f};
      #pragma unroll
      for (int c=0;c<4;c++){
        short8 kf = *(const short8*)((const char*)&Ks[cur][0]
                      + (mt*16+ln)*256 + ((c*64 + g*16) ^ ((ln&7)<<4)));
        acc = __builtin_amdgcn_mfma_f32_16x16x32_bf16(kf, qf[c], acc, 0,0,0);
      }
      st[mt] = acc;
    }

    // causal mask + online softmax (per-lane row stats, q = ln)
    float p[4][4];
    float mtile = -1e30f;
    #pragma unroll
    for (int mt=0; mt<4; mt++)
      #pragma unroll
      for (int r=0;r<4;r++){
        int kv = kv0 + mt*16 + 4*g + r;
        float sv = (kv <= qrow) ? st[mt][r] : -1e30f;
        p[mt][r] = sv;
        mtile = fmaxf(mtile, sv);
      }
    mtile = fmaxf(mtile, __shfl_xor(mtile, 16, 64));
    mtile = fmaxf(mtile, __shfl_xor(mtile, 32, 64));
    float m_new = fmaxf(m_run, mtile);
    float l_tile = 0.f;
    #pragma unroll
    for (int mt=0; mt<4; mt++)
      #pragma unroll
      for (int r=0;r<4;r++){
        float e = exp2f((p[mt][r] - m_new)*LOG2E);
        p[mt][r] = e;
        l_tile += e;
      }
    l_tile += __shfl_xor(l_tile, 16, 64);
    l_tile += __shfl_xor(l_tile, 32, 64);
    float alpha = exp2f((m_run - m_new)*LOG2E);
    l_run = l_run*alpha + l_tile;
    m_run = m_new;
    #pragma unroll
    for (int dt=0;dt<8;dt++) ot[dt] *= alpha;

    // P redistribution per 32-kv half (verified shfl recipe)
    short8 pf[2];
    #pragma unroll
    for (int ks=0; ks<2; ks++){
      unsigned pk00 = packbf(p[2*ks  ][0], p[2*ks  ][1]);
      unsigned pk01 = packbf(p[2*ks  ][2], p[2*ks  ][3]);
      unsigned pk10 = packbf(p[2*ks+1][0], p[2*ks+1][1]);
      unsigned pk11 = packbf(p[2*ks+1][2], p[2*ks+1][3]);
      int src0 = (((2*g  )&3)<<4) | ln;
      int src1 = (((2*g+1)&3)<<4) | ln;
      unsigned t00 = (unsigned)__shfl((int)pk00, src0, 64);
      unsigned t10 = (unsigned)__shfl((int)pk10, src0, 64);
      unsigned t01 = (unsigned)__shfl((int)pk01, src0, 64);
      unsigned t11 = (unsigned)__shfl((int)pk11, src0, 64);
      unsigned u00 = (unsigned)__shfl((int)pk00, src1, 64);
      unsigned u10 = (unsigned)__shfl((int)pk10, src1, 64);
      unsigned u01 = (unsigned)__shfl((int)pk01, src1, 64);
      unsigned u11 = (unsigned)__shfl((int)pk11, src1, 64);
      bool hiv = (g >= 2);
      union { unsigned u[4]; short8 s; } pw;
      pw.u[0] = hiv ? t10 : t00;
      pw.u[1] = hiv ? t11 : t01;
      pw.u[2] = hiv ? u10 : u00;
      pw.u[3] = hiv ? u11 : u01;
      pf[ks] = pw.s;
    }

    // PV: O^T[d][q] += V^T chunks * P^T, A = V from LDS
    #pragma unroll
    for (int dt=0;dt<8;dt++){
      #pragma unroll
      for (int ks=0; ks<2; ks++){
        short8 vf = *(const short8*)((const char*)&Vs[cur][0]
                      + (dt*16+ln)*128 + ((ks*64 + g*16) ^ ((ln&7)<<4)));
        ot[dt] = __builtin_amdgcn_mfma_f32_16x16x32_bf16(vf, pf[ks], ot[dt], 0,0,0);
      }
    }
    __syncthreads();
  }
  #undef STAGE

  float inv = 1.0f / l_run;
  u16* orow = O + (size_t)qrow*(NH*HD) + h*HD;
  #pragma unroll
  for (int dt=0;dt<8;dt++){
    #pragma unroll
    for (int rr=0; rr<4; rr+=2){
      unsigned pkd = packbf(ot[dt][rr]*inv, ot[dt][rr+1]*inv);
      *(unsigned*)(orow + dt*16 + g*4 + rr) = pkd;
    }
  }
}

// ---------------- host ----------------
extern "C" void kernel_launch(void* const* d_in, const int* in_sizes, int n_in,
                              void* d_out, int out_size, void* d_ws, size_t ws_size,
                              hipStream_t stream){
  (void)in_sizes; (void)n_in; (void)out_size; (void)ws_size;
  const float* hs   = (const float*)d_in[0];
  const float* cosb = (const float*)d_in[1];
  const float* sinb = (const float*)d_in[2];
  const float* Wq   = (const float*)d_in[3];
  const float* Wk   = (const float*)d_in[4];
  const float* Wv   = (const float*)d_in[5];
  const float* Wo   = (const float*)d_in[6];
  const float* qw   = (const float*)d_in[7];
  const float* kw   = (const float*)d_in[8];
  float* out = (float*)d_out;

  char* ws = (char*)d_ws;
  u16*   Xb    = (u16*)  (ws);
  u16*   WQKV  = (u16*)  (ws + 16777216);
  float* QKV   = (float*)(ws + 67108864);
  u16*   attnB = (u16*)  (ws + 67108864);   // overlay: QKV dead after norm_rope
  u16*   Qn    = (u16*)  (ws + 117440512);
  u16*   Kn    = (u16*)  (ws + 134217728);
  u16*   Vt    = (u16*)  (ws + 138412032);
  u16*   Wob   = WQKV;                      // overlay: WQKV dead after GEMM1

  cvt_bf16<<<(S_LEN*HIDD/8)/256, 256, 0, stream>>>(hs, Xb, S_LEN*HIDD/8);
  cvt_bf16<<<(NH*HD*HIDD/8)/256, 256, 0, stream>>>(Wq, WQKV, NH*HD*HIDD/8);
  cvt_bf16<<<(NKV*HD*HIDD/8)/256, 256, 0, stream>>>(Wk, WQKV + (size_t)NH*HD*HIDD, NKV*HD*HIDD/8);
  cvt_bf16<<<(NKV*HD*HIDD/8)/256, 256, 0, stream>>>(Wv, WQKV + (size_t)(NH+NKV)*HD*HIDD, NKV*HD*HIDD/8);
  gemm_bt<<<dim3(NQKV/128, S_LEN/128), 256, 0, stream>>>(Xb, WQKV, QKV, S_LEN, NQKV, HIDD);
  norm_rope<<<(S_LEN*48)/4, 256, 0, stream>>>(QKV, cosb, sinb, qw, kw, Qn, Kn, Vt);
  cvt_bf16<<<(HIDD*NH*HD/8)/256, 256, 0, stream>>>(Wo, Wob, HIDD*NH*HD/8);
  flash_attn<<<dim3(S_LEN/64, NH), 256, 0, stream>>>(Qn, Kn, Vt, attnB);
  gemm_bt<<<dim3(HIDD/128, S_LEN/128), 256, 0, stream>>>(attnB, Wob, out, S_LEN, HIDD, HIDD);
}

// Round 3
// 502.571 us; speedup vs baseline: 1.6212x; 1.0193x over previous
//
#include <hip/hip_runtime.h>
#include <hip/hip_bf16.h>
#include <stdint.h>

#define S_LEN 2048
#define HIDD  4096
#define NH    32
#define NKV   8
#define HD    128
#define NQKV  6144   // (NH + 2*NKV) * HD
#define ATT_SCALE 0.08838834764831845f
#define LOG2E 1.4426950408889634f

typedef unsigned short u16;
typedef __attribute__((ext_vector_type(8))) short short8;
typedef __attribute__((ext_vector_type(4))) float f32x4;

__device__ __forceinline__ unsigned f2bfbits(float f){
  union{float f; unsigned u;} v; v.f = f;
  return (v.u + 0x7FFFu + ((v.u>>16)&1u)) >> 16;
}
__device__ __forceinline__ unsigned packbf(float a, float b){
  return f2bfbits(a) | (f2bfbits(b)<<16);
}

#define GLOAD16(g, l) __builtin_amdgcn_global_load_lds( \
    (__attribute__((address_space(1))) void*)(g), \
    (__attribute__((address_space(3))) void*)(l), 16, 0, 0)

#define VMWAIT(n) asm volatile("s_waitcnt vmcnt(" #n ")" ::: "memory")

// ---------------- fp32 -> bf16 convert (8 elems/thread) ----------------
__global__ __launch_bounds__(256) void cvt_bf16(const float* __restrict__ in,
                                                u16* __restrict__ out, int n8){
  int i = blockIdx.x*256 + threadIdx.x;
  if (i >= n8) return;
  const float4* p = (const float4*)in;
  float4 a = p[2*i], b = p[2*i+1];
  union { unsigned u[4]; short8 s; } o;
  o.u[0] = packbf(a.x, a.y); o.u[1] = packbf(a.z, a.w);
  o.u[2] = packbf(b.x, b.y); o.u[3] = packbf(b.z, b.w);
  *(short8*)(out + (size_t)i*8) = o.s;
}

// ============ big-tile pipelined bf16 GEMM, C = A * B^T (fp32 C) ============
// BM x 256 tile, BK=32, 8 waves (2M x 4N), 4-deep circular LDS buffer,
// counted vmcnt (never drains in main loop), st_16x32 LDS swizzle (T2),
// setprio around MFMA clusters (T5), raw s_barrier (no vmcnt(0) drain).
// LDS swizzle: byte(row,k) = (row>>4)*1024 + (row&15)*64 + 2*(k ^ ((row>>3&1)<<4))
// staged via linear LDS dest + inverse-swizzled global source (both-sides rule).
template<int BM>
__global__ __launch_bounds__(512) void gemm_bt_big(const u16* __restrict__ A,
                                                   const u16* __restrict__ B,
                                                   float* __restrict__ C,
                                                   int N, int K, int nbx){
  constexpr int MREP   = BM/32;     // M fragments per wave (8 or 4)
  constexpr int AH     = BM/128;    // A half-tiles per K-tile (2 or 1)
  constexpr int ABYTES = BM*64;     // A bytes per K-tile buffer
  __shared__ __align__(16) u16 Als[4*BM*32];
  __shared__ __align__(16) u16 Bls[4*256*32];

  const int tid = threadIdx.x;
  const int w = tid>>6, lane = tid&63, ln = lane&15, g = lane>>4;
  const int wm = w>>2, wn = w&3;
  const int swz5 = ((ln>>3)&1)<<5;

  // XCD-chunked block swizzle (grid % 8 == 0 for both GEMMs)
  const int nwg = gridDim.x;
  const int flat = blockIdx.x;
  const int wg = (flat&7)*(nwg>>3) + (flat>>3);
  const int by = wg / nbx;
  const int bx = wg - by*nbx;
  const int m0 = by*BM, n0 = bx*256;

  // staging: thread tid stages 16B slot s=tid of each half-tile.
  // row(s) = (s>>6)*16 + ((s&63)>>2); k_src = (s&3)*8 ^ ((s>>5&1)<<4)
  const int rs = ((tid>>6)<<4) + ((tid&63)>>2);
  const int ks = ((tid&3)<<3) ^ (((tid>>5)&1)<<4);
  const u16* srcA[AH];
  #pragma unroll
  for (int h=0; h<AH; h++) srcA[h] = A + (size_t)(m0 + h*128 + rs)*K + ks;
  const u16* srcB[2];
  #pragma unroll
  for (int h=0; h<2; h++) srcB[h] = B + (size_t)(n0 + h*128 + rs)*K + ks;
  char* Adst = (char*)Als + w*1024;
  char* Bdst = (char*)Bls + w*1024;

  const int NT = K>>5;

  #define STAGE_T(t) { const int bi_ = (t)&3; const int ko_ = (t)<<5;            \
    _Pragma("unroll")                                                            \
    for (int h=0;h<AH;h++) GLOAD16(srcA[h] + ko_, Adst + bi_*ABYTES + h*8192);   \
    _Pragma("unroll")                                                            \
    for (int h=0;h<2;h++)  GLOAD16(srcB[h] + ko_, Bdst + bi_*16384 + h*8192); }

  f32x4 acc[MREP][4];
  #pragma unroll
  for (int m=0;m<MREP;m++)
    #pragma unroll
    for (int n=0;n<4;n++) acc[m][n] = (f32x4){0.f,0.f,0.f,0.f};

  STAGE_T(0); STAGE_T(1); STAGE_T(2);

  auto compute_tile = [&](int bi){
    const char* Ab = (const char*)Als + bi*ABYTES;
    const char* Bb = (const char*)Bls + bi*16384;
    short8 bfr[4];
    #pragma unroll
    for (int n=0;n<4;n++)
      bfr[n] = *(const short8*)(Bb + (wn*4+n)*1024 + ln*64 + ((g*16)^swz5));
    short8 afr[4];
    #pragma unroll
    for (int m=0;m<4;m++)
      afr[m] = *(const short8*)(Ab + (wm*MREP+m)*1024 + ln*64 + ((g*16)^swz5));
    __builtin_amdgcn_s_setprio(1);
    #pragma unroll
    for (int m=0;m<4;m++)
      #pragma unroll
      for (int n=0;n<4;n++)
        acc[m][n] = __builtin_amdgcn_mfma_f32_16x16x32_bf16(afr[m], bfr[n], acc[m][n], 0,0,0);
    __builtin_amdgcn_s_setprio(0);
    if constexpr (BM==256){
      __builtin_amdgcn_s_barrier();
      short8 af2[4];
      #pragma unroll
      for (int m=0;m<4;m++)
        af2[m] = *(const short8*)(Ab + (wm*8+4+m)*1024 + ln*64 + ((g*16)^swz5));
      __builtin_amdgcn_s_setprio(1);
      #pragma unroll
      for (int m=0;m<4;m++)
        #pragma unroll
        for (int n=0;n<4;n++)
          acc[4+m][n] = __builtin_amdgcn_mfma_f32_16x16x32_bf16(af2[m], bfr[n], acc[4+m][n], 0,0,0);
      __builtin_amdgcn_s_setprio(0);
    }
    __builtin_amdgcn_s_barrier();
  };

  // main loop: stage 3 tiles ahead, counted vmcnt (current tile resident)
  for (int T=0; T<NT-3; T++){
    STAGE_T(T+3);
    if constexpr (BM==256) VMWAIT(12); else VMWAIT(9);
    __builtin_amdgcn_s_barrier();
    compute_tile(T&3);
  }
  // tail: drain progressively
  if constexpr (BM==256) VMWAIT(8); else VMWAIT(6);
  __builtin_amdgcn_s_barrier();
  compute_tile((NT-3)&3);
  if constexpr (BM==256) VMWAIT(4); else VMWAIT(3);
  __builtin_amdgcn_s_barrier();
  compute_tile((NT-2)&3);
  VMWAIT(0);
  __builtin_amdgcn_s_barrier();
  compute_tile((NT-1)&3);
  #undef STAGE_T

  #pragma unroll
  for (int m=0;m<MREP;m++)
    #pragma unroll
    for (int n=0;n<4;n++)
      #pragma unroll
      for (int r=0;r<4;r++){
        int row = m0 + wm*(BM/2) + m*16 + g*4 + r;
        int col = n0 + wn*64 + n*16 + ln;
        C[(size_t)row*N + col] = acc[m][n][r];
      }
}

// ---------------- RMSNorm + RoPE + layout (1 wave per (s, head-slot) row) -----
__global__ __launch_bounds__(256) void norm_rope(const float* __restrict__ QKV,
                                                 const float* __restrict__ cosb,
                                                 const float* __restrict__ sinb,
                                                 const float* __restrict__ qw,
                                                 const float* __restrict__ kw,
                                                 u16* __restrict__ Qn,
                                                 u16* __restrict__ Kn,
                                                 u16* __restrict__ Vt){
  int w = threadIdx.x>>6, lane = threadIdx.x&63;
  int row = blockIdx.x*4 + w;              // 0 .. S*48-1
  int s = row / 48, slot = row - s*48;
  const float* src = QKV + (size_t)s*NQKV + slot*HD;
  float x0 = src[lane], x1 = src[lane+64];
  if (slot < 40){
    float ss = x0*x0 + x1*x1;
    #pragma unroll
    for (int off=1; off<64; off<<=1) ss += __shfl_xor(ss, off, 64);
    float r = rsqrtf(ss*(1.0f/128.0f) + 1e-6f);
    const float* wgt = (slot < 32) ? qw : kw;
    float y0 = x0*r*wgt[lane], y1 = x1*r*wgt[lane+64];
    float c0 = cosb[(size_t)s*HD+lane], c1 = cosb[(size_t)s*HD+lane+64];
    float s0 = sinb[(size_t)s*HD+lane], s1 = sinb[(size_t)s*HD+lane+64];
    float o0 = y0*c0 - y1*s0;
    float o1 = y1*c1 + y0*s1;
    float sc = (slot < 32) ? ATT_SCALE : 1.0f;
    u16* dst = (slot < 32) ? (Qn + ((size_t)slot*S_LEN + s)*HD)
                           : (Kn + ((size_t)(slot-32)*S_LEN + s)*HD);
    dst[lane]    = (u16)f2bfbits(o0*sc);
    dst[lane+64] = (u16)f2bfbits(o1*sc);
  } else {
    int kvh = slot - 40;
    u16* dst = Vt + (size_t)kvh*HD*S_LEN + s;
    dst[(size_t)lane*S_LEN]      = (u16)f2bfbits(x0);
    dst[(size_t)(lane+64)*S_LEN] = (u16)f2bfbits(x1);
  }
}

// ---------------- flash attention v2 (causal, GQA) ----------------
__global__ __launch_bounds__(256) void flash_attn(const u16* __restrict__ Qn,
                                                  const u16* __restrict__ Kn,
                                                  const u16* __restrict__ Vt,
                                                  u16* __restrict__ O){
  __shared__ u16 Ks[2][64*128];   // [kv][d] swizzled, 16KB each
  __shared__ u16 Vs[2][128*64];   // [d][kv] swizzled, 16KB each

  const int h = blockIdx.y;
  const int qb = gridDim.x - 1 - blockIdx.x;   // big blocks first
  const int q0 = qb*64;
  const int w = threadIdx.x>>6, lane = threadIdx.x&63, ln = lane&15, g = lane>>4;
  const int kvh = h>>2;                        // NH/NKV = 4
  const int qrow = q0 + w*16 + ln;
  const u16* Qh = Qn + (size_t)h*S_LEN*HD;
  const u16* Kh = Kn + (size_t)kvh*S_LEN*HD;
  const u16* Vh = Vt + (size_t)kvh*HD*S_LEN;

  short8 qf[4];
  #pragma unroll
  for (int c=0;c<4;c++)
    qf[c] = *(const short8*)(Qh + (size_t)qrow*HD + c*32 + g*8);

  f32x4 ot[8];
  #pragma unroll
  for (int dt=0;dt<8;dt++) ot[dt] = (f32x4){0.f,0.f,0.f,0.f};
  float m_run = -1e30f, l_run = 0.f;

  const int nt = qb + 1;

  const int krow_w = w*4 + g;
  const int ksw    = ((krow_w)&7)<<4;
  const int kcol   = ((ln*16) ^ ksw) >> 1;
  const int vrow_w = w*8 + (lane>>3);
  const int vsw    = ((lane>>3)&7)<<4;
  const int vcol   = (((lane&7)*16) ^ vsw) >> 1;

  #define STAGE(bufi, t) { \
    int kv0_ = (t)*64; \
    _Pragma("unroll") \
    for (int p=0;p<4;p++){ \
      const u16* ga = Kh + (size_t)(kv0_ + p*16 + krow_w)*HD + kcol; \
      GLOAD16(ga, (char*)&Ks[bufi][0] + p*4096 + w*1024); \
      const u16* gv = Vh + (size_t)(p*32 + vrow_w)*S_LEN + kv0_ + vcol; \
      GLOAD16(gv, (char*)&Vs[bufi][0] + p*4096 + w*1024); \
    } \
  }

  STAGE(0, 0);
  __syncthreads();

  for (int t=0; t<nt; ++t){
    const int cur = t&1;
    if (t+1 < nt) STAGE(cur^1, t+1);
    const int kv0 = t*64;

    f32x4 st[4];
    #pragma unroll
    for (int mt=0; mt<4; mt++){
      f32x4 acc = (f32x4){0.f,0.f,0.f,0.f};
      #pragma unroll
      for (int c=0;c<4;c++){
        short8 kf = *(const short8*)((const char*)&Ks[cur][0]
                      + (mt*16+ln)*256 + ((c*64 + g*16) ^ ((ln&7)<<4)));
        acc = __builtin_amdgcn_mfma_f32_16x16x32_bf16(kf, qf[c], acc, 0,0,0);
      }
      st[mt] = acc;
    }

    float p[4][4];
    float mtile = -1e30f;
    #pragma unroll
    for (int mt=0; mt<4; mt++)
      #pragma unroll
      for (int r=0;r<4;r++){
        int kv = kv0 + mt*16 + 4*g + r;
        float sv = (kv <= qrow) ? st[mt][r] : -1e30f;
        p[mt][r] = sv;
        mtile = fmaxf(mtile, sv);
      }
    mtile = fmaxf(mtile, __shfl_xor(mtile, 16, 64));
    mtile = fmaxf(mtile, __shfl_xor(mtile, 32, 64));
    float m_new = fmaxf(m_run, mtile);
    float l_tile = 0.f;
    #pragma unroll
    for (int mt=0; mt<4; mt++)
      #pragma unroll
      for (int r=0;r<4;r++){
        float e = exp2f((p[mt][r] - m_new)*LOG2E);
        p[mt][r] = e;
        l_tile += e;
      }
    l_tile += __shfl_xor(l_tile, 16, 64);
    l_tile += __shfl_xor(l_tile, 32, 64);
    float alpha = exp2f((m_run - m_new)*LOG2E);
    l_run = l_run*alpha + l_tile;
    m_run = m_new;
    #pragma unroll
    for (int dt=0;dt<8;dt++) ot[dt] *= alpha;

    short8 pf[2];
    #pragma unroll
    for (int ks=0; ks<2; ks++){
      unsigned pk00 = packbf(p[2*ks  ][0], p[2*ks  ][1]);
      unsigned pk01 = packbf(p[2*ks  ][2], p[2*ks  ][3]);
      unsigned pk10 = packbf(p[2*ks+1][0], p[2*ks+1][1]);
      unsigned pk11 = packbf(p[2*ks+1][2], p[2*ks+1][3]);
      int src0 = (((2*g  )&3)<<4) | ln;
      int src1 = (((2*g+1)&3)<<4) | ln;
      unsigned t00 = (unsigned)__shfl((int)pk00, src0, 64);
      unsigned t10 = (unsigned)__shfl((int)pk10, src0, 64);
      unsigned t01 = (unsigned)__shfl((int)pk01, src0, 64);
      unsigned t11 = (unsigned)__shfl((int)pk11, src0, 64);
      unsigned u00 = (unsigned)__shfl((int)pk00, src1, 64);
      unsigned u10 = (unsigned)__shfl((int)pk10, src1, 64);
      unsigned u01 = (unsigned)__shfl((int)pk01, src1, 64);
      unsigned u11 = (unsigned)__shfl((int)pk11, src1, 64);
      bool hiv = (g >= 2);
      union { unsigned u[4]; short8 s; } pw;
      pw.u[0] = hiv ? t10 : t00;
      pw.u[1] = hiv ? t11 : t01;
      pw.u[2] = hiv ? u10 : u00;
      pw.u[3] = hiv ? u11 : u01;
      pf[ks] = pw.s;
    }

    #pragma unroll
    for (int dt=0;dt<8;dt++){
      #pragma unroll
      for (int ks=0; ks<2; ks++){
        short8 vf = *(const short8*)((const char*)&Vs[cur][0]
                      + (dt*16+ln)*128 + ((ks*64 + g*16) ^ ((ln&7)<<4)));
        ot[dt] = __builtin_amdgcn_mfma_f32_16x16x32_bf16(vf, pf[ks], ot[dt], 0,0,0);
      }
    }
    __syncthreads();
  }
  #undef STAGE

  float inv = 1.0f / l_run;
  u16* orow = O + (size_t)qrow*(NH*HD) + h*HD;
  #pragma unroll
  for (int dt=0;dt<8;dt++){
    #pragma unroll
    for (int rr=0; rr<4; rr+=2){
      unsigned pkd = packbf(ot[dt][rr]*inv, ot[dt][rr+1]*inv);
      *(unsigned*)(orow + dt*16 + g*4 + rr) = pkd;
    }
  }
}

// ---------------- host ----------------
extern "C" void kernel_launch(void* const* d_in, const int* in_sizes, int n_in,
                              void* d_out, int out_size, void* d_ws, size_t ws_size,
                              hipStream_t stream){
  (void)in_sizes; (void)n_in; (void)out_size; (void)ws_size;
  const float* hs   = (const float*)d_in[0];
  const float* cosb = (const float*)d_in[1];
  const float* sinb = (const float*)d_in[2];
  const float* Wq   = (const float*)d_in[3];
  const float* Wk   = (const float*)d_in[4];
  const float* Wv   = (const float*)d_in[5];
  const float* Wo   = (const float*)d_in[6];
  const float* qw   = (const float*)d_in[7];
  const float* kw   = (const float*)d_in[8];
  float* out = (float*)d_out;

  char* ws = (char*)d_ws;
  u16*   Xb    = (u16*)  (ws);
  u16*   WQKV  = (u16*)  (ws + 16777216);
  float* QKV   = (float*)(ws + 67108864);
  u16*   attnB = (u16*)  (ws + 67108864);   // overlay: QKV dead after norm_rope
  u16*   Qn    = (u16*)  (ws + 117440512);
  u16*   Kn    = (u16*)  (ws + 134217728);
  u16*   Vt    = (u16*)  (ws + 138412032);
  u16*   Wob   = WQKV;                      // overlay: WQKV dead after GEMM1

  cvt_bf16<<<(S_LEN*HIDD/8)/256, 256, 0, stream>>>(hs, Xb, S_LEN*HIDD/8);
  cvt_bf16<<<(NH*HD*HIDD/8)/256, 256, 0, stream>>>(Wq, WQKV, NH*HD*HIDD/8);
  cvt_bf16<<<(NKV*HD*HIDD/8)/256, 256, 0, stream>>>(Wk, WQKV + (size_t)NH*HD*HIDD, NKV*HD*HIDD/8);
  cvt_bf16<<<(NKV*HD*HIDD/8)/256, 256, 0, stream>>>(Wv, WQKV + (size_t)(NH+NKV)*HD*HIDD, NKV*HD*HIDD/8);
  // GEMM1: [2048 x 4096] x [6144 x 4096]^T -> 8 x 24 = 192 blocks (BM=256)
  gemm_bt_big<256><<<192, 512, 0, stream>>>(Xb, WQKV, QKV, NQKV, HIDD, NQKV/256);
  norm_rope<<<(S_LEN*48)/4, 256, 0, stream>>>(QKV, cosb, sinb, qw, kw, Qn, Kn, Vt);
  cvt_bf16<<<(HIDD*NH*HD/8)/256, 256, 0, stream>>>(Wo, Wob, HIDD*NH*HD/8);
  flash_attn<<<dim3(S_LEN/64, NH), 256, 0, stream>>>(Qn, Kn, Vt, attnB);
  // GEMM2: [2048 x 4096] x [4096 x 4096]^T -> 16 x 16 = 256 blocks (BM=128)
  gemm_bt_big<128><<<256, 512, 0, stream>>>(attnB, Wob, out, HIDD, HIDD, HIDD/256);
}